// Round 12
// baseline (212.215 us; speedup 1.0000x reference)
//
#include <hip/hip_runtime.h>

typedef unsigned short u16;
typedef __bf16 bf16x8 __attribute__((ext_vector_type(8)));
typedef float f32x4 __attribute__((ext_vector_type(4)));
typedef u16 u16x8 __attribute__((ext_vector_type(8)));

#define B_ 16384

__device__ __forceinline__ u16 f2b(float f){
  unsigned u = __builtin_bit_cast(unsigned, f);
  u = (u + 0x7FFFu + ((u >> 16) & 1u)) >> 16;   // RNE
  return (u16)u;
}
__device__ __forceinline__ float b2f(u16 v){
  return __builtin_bit_cast(float, ((unsigned)v) << 16);
}
__device__ __forceinline__ void ld8(const u16* __restrict__ p, float* f){
  u16x8 v = *(const u16x8*)p;
  #pragma unroll
  for (int j = 0; j < 8; ++j) f[j] = b2f(v[j]);
}
__device__ __forceinline__ void st8(u16* __restrict__ p, const float* f){
  u16x8 v;
  #pragma unroll
  for (int j = 0; j < 8; ++j) v[j] = f2b(f[j]);
  *(u16x8*)p = v;
}

__device__ __forceinline__ void gload16(const u16* g, u16* lds){
  __builtin_amdgcn_global_load_lds(
      (const __attribute__((address_space(1))) unsigned int*)g,
      (__attribute__((address_space(3))) unsigned int*)lds, 16, 0, 0);
}

// ===== core128q: 128x256 block tile, 2 waves, per-wave 128x128 (acc[8][8]) ==
// Rationale (R11 cycle model): LDS bytes/FLOP = (Wm+Wn)/(Wm*Wn); at 64x64 or
// 64x128 wave tiles LDS (85 B/cyc) is 68-86% of the critical path. 128x128
// halves it -> MFMA becomes the long pole (1242 vs 578 cyc per CU-step).
// acc[8][8] = 256 VGPR (+~50 misc; no-spill verified to 450 per m08);
// 1 wave/SIMD -> all hiding is intra-wave ILP (16 ds_reads pipelined ahead
// of 64 independent MFMAs; compiler emits fine-grained lgkmcnt).
// LDS: slot = A[128][32] + B[256][32] = 24 KB; ring-3 = 72 KB -> 2 blocks/CU.
// R9-verified 0-conflict row-pair layout; counted vmcnt(12) (depth-2 ring,
// never drain-0 in steady state). Staging: 24 chunks of 1 KB, 12 per wave.
__device__ __forceinline__ void core128q(const u16* __restrict__ A,
                                         const u16* __restrict__ Wt,
                                         int K, int m0, int n0, int nt,
                                         u16* sm, f32x4 acc[8][8])
{
  const int tid = threadIdx.x, lane = tid & 63, wave = tid >> 6;  // 0..1
  const int wn = wave * 128;

  #pragma unroll
  for (int m = 0; m < 8; ++m)
    #pragma unroll
    for (int n = 0; n < 8; ++n) acc[m][n] = (f32x4){0.f, 0.f, 0.f, 0.f};

  // staging: chunks 0..7 = A rows c*16.., 8..23 = B rows (c-8)*16..; 12/wave
  const int s_    = (lane & 7) ^ ((lane >> 3) & 7);   // logical slot (involution)
  const int srow2 = 2 * (lane >> 3) + (s_ >> 2);      // row within 16-row chunk
  const int sk    = (s_ & 3) * 8;                     // k elem offset
  const u16* gsrc[12];
  int gdst[12];
  #pragma unroll
  for (int i = 0; i < 12; ++i) {
    int c = wave * 12 + i;
    if (c < 8) {
      gsrc[i] = A + (size_t)(m0 + c * 16 + srow2) * K + sk;
      gdst[i] = c * 512;
    } else {
      gsrc[i] = Wt + (size_t)(n0 + (c - 8) * 16 + srow2) * K + sk;
      gdst[i] = 4096 + (c - 8) * 512;
    }
  }

  // ds-read offsets (row-pair layout: line L = r>>1, s' = (r&1)*4 + k4)
  int aoff[8], boff[8];
  #pragma unroll
  for (int m = 0; m < 8; ++m) {
    int r = m * 16 + (lane & 15);
    int L = r >> 1;
    int phys = (((r & 1) << 2) + (lane >> 4)) ^ (L & 7);
    aoff[m] = L * 64 + phys * 8;
  }
  #pragma unroll
  for (int n = 0; n < 8; ++n) {
    int r = wn + n * 16 + (lane & 15);
    int L = r >> 1;
    int phys = (((r & 1) << 2) + (lane >> 4)) ^ (L & 7);
    boff[n] = 4096 + L * 64 + phys * 8;
  }

  // prologue: stage steps 0,1 into slots 0,1 (24 loads/wave)
  #pragma unroll
  for (int j = 0; j < 2; ++j) {
    u16* sl = sm + j * 12288;
    #pragma unroll
    for (int i = 0; i < 12; ++i) gload16(gsrc[i] + j * 32, sl + gdst[i]);
  }
  asm volatile("s_waitcnt vmcnt(12)" ::: "memory");   // step 0 landed
  __builtin_amdgcn_s_barrier();

  int cs = 0;
  for (int j = 0; j < nt; ++j) {
    if (j + 2 < nt) {                       // stage j+2 into slot of step j-1
      int ns = cs + 2; ns = (ns >= 3) ? ns - 3 : ns;
      u16* sl = sm + ns * 12288;
      #pragma unroll
      for (int i = 0; i < 12; ++i) gload16(gsrc[i] + (size_t)(j + 2) * 32, sl + gdst[i]);
    }
    const u16* sa = sm + cs * 12288;
    bf16x8 av[8], bv[8];
    #pragma unroll
    for (int m = 0; m < 8; ++m) av[m] = *(const bf16x8*)(sa + aoff[m]);
    #pragma unroll
    for (int n = 0; n < 8; ++n) bv[n] = *(const bf16x8*)(sa + boff[n]);
    __builtin_amdgcn_s_setprio(1);
    #pragma unroll
    for (int m = 0; m < 8; ++m)
      #pragma unroll
      for (int n = 0; n < 8; ++n)
        acc[m][n] = __builtin_amdgcn_mfma_f32_16x16x32_bf16(av[m], bv[n], acc[m][n], 0, 0, 0);
    __builtin_amdgcn_s_setprio(0);
    if (j + 2 < nt)      asm volatile("s_waitcnt vmcnt(12)" ::: "memory");
    else if (j + 1 < nt) asm volatile("s_waitcnt vmcnt(0)" ::: "memory");
    __builtin_amdgcn_s_barrier();
    cs = (cs == 2) ? 0 : cs + 1;
  }
}

// ===== core32 (R9/R10-proven, kept for gemm1) =====
__device__ __forceinline__ void core32(const u16* __restrict__ A,
                                       const u16* __restrict__ Wt,
                                       int K, int m0, int n0, int nt,
                                       u16* sm, f32x4 acc[4][4])
{
  const int tid = threadIdx.x, lane = tid & 63, wave = tid >> 6;
  const int wm = ((tid >> 7) & 3) * 64;
  const int wn = ((tid >> 6) & 1) * 64;

  #pragma unroll
  for (int m = 0; m < 4; ++m)
    #pragma unroll
    for (int n = 0; n < 4; ++n) acc[m][n] = (f32x4){0.f, 0.f, 0.f, 0.f};

  const int s_    = (lane & 7) ^ ((lane >> 3) & 7);
  const int srow2 = 2 * (lane >> 3) + (s_ >> 2);
  const int sk    = (s_ & 3) * 8;
  const u16* gsrc[3];
  int gdst[3];
  #pragma unroll
  for (int i = 0; i < 3; ++i) {
    int c = wave * 3 + i;
    if (c < 16) {
      gsrc[i] = A + (size_t)(m0 + c * 16 + srow2) * K + sk;
      gdst[i] = c * 512;
    } else {
      gsrc[i] = Wt + (size_t)(n0 + (c - 16) * 16 + srow2) * K + sk;
      gdst[i] = 8192 + (c - 16) * 512;
    }
  }

  int aoff[4], boff[4];
  #pragma unroll
  for (int m = 0; m < 4; ++m) {
    int r = wm + m * 16 + (lane & 15);
    int L = r >> 1;
    int phys = (((r & 1) << 2) + (lane >> 4)) ^ (L & 7);
    aoff[m] = L * 64 + phys * 8;
  }
  #pragma unroll
  for (int n = 0; n < 4; ++n) {
    int r = wn + n * 16 + (lane & 15);
    int L = r >> 1;
    int phys = (((r & 1) << 2) + (lane >> 4)) ^ (L & 7);
    boff[n] = 8192 + L * 64 + phys * 8;
  }

  #pragma unroll
  for (int j = 0; j < 2; ++j) {
    u16* sl = sm + j * 12288;
    #pragma unroll
    for (int i = 0; i < 3; ++i) gload16(gsrc[i] + j * 32, sl + gdst[i]);
  }
  asm volatile("s_waitcnt vmcnt(3)" ::: "memory");
  __builtin_amdgcn_s_barrier();

  int cs = 0;
  for (int j = 0; j < nt; ++j) {
    if (j + 2 < nt) {
      int ns = cs + 2; ns = (ns >= 3) ? ns - 3 : ns;
      u16* sl = sm + ns * 12288;
      #pragma unroll
      for (int i = 0; i < 3; ++i) gload16(gsrc[i] + (size_t)(j + 2) * 32, sl + gdst[i]);
    }
    const u16* sa = sm + cs * 12288;
    bf16x8 av[4], bv[4];
    #pragma unroll
    for (int m = 0; m < 4; ++m) av[m] = *(const bf16x8*)(sa + aoff[m]);
    #pragma unroll
    for (int n = 0; n < 4; ++n) bv[n] = *(const bf16x8*)(sa + boff[n]);
    __builtin_amdgcn_s_setprio(1);
    #pragma unroll
    for (int m = 0; m < 4; ++m)
      #pragma unroll
      for (int n = 0; n < 4; ++n)
        acc[m][n] = __builtin_amdgcn_mfma_f32_16x16x32_bf16(av[m], bv[n], acc[m][n], 0, 0, 0);
    __builtin_amdgcn_s_setprio(0);
    if (j + 2 < nt)      asm volatile("s_waitcnt vmcnt(3)" ::: "memory");
    else if (j + 1 < nt) asm volatile("s_waitcnt vmcnt(0)" ::: "memory");
    __builtin_amdgcn_s_barrier();
    cs = (cs == 2) ? 0 : cs + 1;
  }
}

// ---------------- stage kernels ----------------

// GEMM0: xb[16384,512] x Wt0[2816,512]^T. grid 1408 = 128 m x 11 n-panels(256).
__global__ __launch_bounds__(128, 1) void k_gemm0(const u16* __restrict__ xb,
    const u16* __restrict__ Wt0, const float* __restrict__ bias0,
    u16* __restrict__ E0, float* __restrict__ G0L)
{
  __shared__ __align__(16) u16 sm[36864];
  f32x4 acc[8][8];
  const int bid = blockIdx.x;                 // 1408 = 8 * 176
  const int swz = (bid & 7) * 176 + (bid >> 3);
  const int m0 = (swz / 11) * 128, n0 = (swz % 11) * 256;
  core128q(xb, Wt0, 512, m0, n0, 16, sm, acc);
  const int lane = threadIdx.x & 63;
  const int wn = (threadIdx.x >> 6) * 128;
  #pragma unroll
  for (int mi = 0; mi < 8; ++mi)
    #pragma unroll
    for (int ni = 0; ni < 8; ++ni) {
      int gcol = n0 + wn + ni * 16 + (lane & 15);
      float bias = bias0[gcol];
      #pragma unroll
      for (int q = 0; q < 4; ++q) {
        int grow = m0 + mi * 16 + ((lane >> 4) << 2) + q;
        float v = acc[mi][ni][q] + bias;
        if (gcol < 2560)      E0[(size_t)grow * 2560 + gcol] = f2b(fmaxf(v, 0.f));
        else if (gcol < 2586) G0L[(size_t)grow * 26 + (gcol - 2560)] = v;
      }
    }
}

// MIX0 + fused gate1 (R10-proven): 8 rows/block, 32-lane half-wave per row.
__global__ __launch_bounds__(256) void k_mix0(const u16* __restrict__ E0,
    const float* __restrict__ G0L, const float* __restrict__ WG1T,
    const float* __restrict__ b_gate1, u16* __restrict__ T1SH,
    float* __restrict__ G1S)
{
  const int b = blockIdx.x * 8 + (threadIdx.x >> 5);
  const int e0 = (threadIdx.x & 31) * 8;
  const float* gl = G0L + (size_t)b * 26;
  float g[4][4];
  #pragma unroll
  for (int t = 0; t < 4; ++t) {
    float l0 = gl[t*4+0], l1 = gl[t*4+1], l2 = gl[t*4+2], l3 = gl[t*4+3];
    float m = fmaxf(fmaxf(l0, l1), fmaxf(l2, l3));
    float e0e = expf(l0-m), e1 = expf(l1-m), e2 = expf(l2-m), e3 = expf(l3-m);
    float inv = 1.f / (e0e + e1 + e2 + e3);
    g[t][0] = e0e*inv; g[t][1] = e1*inv; g[t][2] = e2*inv; g[t][3] = e3*inv;
  }
  float gs[10];
  {
    float m = gl[16];
    #pragma unroll
    for (int j = 1; j < 10; ++j) m = fmaxf(m, gl[16 + j]);
    float s = 0.f;
    #pragma unroll
    for (int j = 0; j < 10; ++j) { gs[j] = expf(gl[16 + j] - m); s += gs[j]; }
    float inv = 1.f / s;
    #pragma unroll
    for (int j = 0; j < 10; ++j) gs[j] *= inv;
  }
  const u16* row = E0 + (size_t)b * 2560;
  float sh0[8], sh1[8], shacc[8];
  ld8(row + 2048 + e0, sh0);
  ld8(row + 2304 + e0, sh1);
  #pragma unroll
  for (int j = 0; j < 8; ++j) shacc[j] = gs[8]*sh0[j] + gs[9]*sh1[j];
  float gp[16];
  #pragma unroll
  for (int t = 0; t < 4; ++t) {
    float te0[8], te1[8], v[8];
    ld8(row + (t*2+0)*256 + e0, te0);
    ld8(row + (t*2+1)*256 + e0, te1);
    #pragma unroll
    for (int j = 0; j < 8; ++j) {
      v[j] = g[t][0]*te0[j] + g[t][1]*te1[j] + g[t][2]*sh0[j] + g[t][3]*sh1[j];
      shacc[j] += gs[t*2+0]*te0[j] + gs[t*2+1]*te1[j];
    }
    st8(T1SH + ((size_t)t * B_ + b) * 256 + e0, v);
    #pragma unroll
    for (int gg = 0; gg < 4; ++gg) {
      const float* wv = WG1T + ((size_t)(t * 4 + gg) * 256 + e0);
      float s = 0.f;
      #pragma unroll
      for (int j = 0; j < 8; ++j) s += v[j] * wv[j];
      gp[t * 4 + gg] = s;
    }
  }
  st8(T1SH + ((size_t)4 * B_ + b) * 256 + e0, shacc);
  #pragma unroll
  for (int i = 0; i < 16; ++i) {
    #pragma unroll
    for (int off = 1; off < 32; off <<= 1)
      gp[i] += __shfl_xor(gp[i], off, 32);
  }
  if ((threadIdx.x & 31) == 0) {
    float* orow = G1S + (size_t)b * 16;
    #pragma unroll
    for (int z = 0; z < 4; ++z) {
      float l0 = gp[z*4+0] + b_gate1[z*4+0];
      float l1 = gp[z*4+1] + b_gate1[z*4+1];
      float l2 = gp[z*4+2] + b_gate1[z*4+2];
      float l3 = gp[z*4+3] + b_gate1[z*4+3];
      float m = fmaxf(fmaxf(l0, l1), fmaxf(l2, l3));
      float x0 = expf(l0-m), x1 = expf(l1-m), x2 = expf(l2-m), x3 = expf(l3-m);
      float inv = 1.f / (x0 + x1 + x2 + x3);
      orow[z*4+0] = x0*inv; orow[z*4+1] = x1*inv;
      orow[z*4+2] = x2*inv; orow[z*4+3] = x3*inv;
    }
  }
}

// GEMM1: 20 panels (z 0..4 x 4 n-tiles of 128) x 64 m-blocks, core32.
__global__ __launch_bounds__(512) void k_gemm1(const u16* __restrict__ T1SH,
    const u16* __restrict__ Wt1, const float* __restrict__ bias1,
    u16* __restrict__ E1, u16* __restrict__ SH1E)
{
  __shared__ __align__(16) u16 sm[36864];
  f32x4 acc[4][4];
  const int bid = blockIdx.x;                 // 1280 = 8 * 160
  const int swz = (bid & 7) * 160 + (bid >> 3);
  const int mi_ = swz / 20, pan = swz % 20;
  const int z  = pan >> 2;
  const int n0 = (pan & 3) * 128;
  const int m0 = mi_ * 256;
  core32(T1SH + (size_t)z * B_ * 256, Wt1 + (size_t)z * 512 * 256, 256, m0, n0, 8, sm, acc);
  const int lane = threadIdx.x & 63;
  const int wm = ((threadIdx.x >> 7) & 3) * 64, wn = ((threadIdx.x >> 6) & 1) * 64;
  const float* bias = bias1 + z * 512;
  #pragma unroll
  for (int mi = 0; mi < 4; ++mi)
    #pragma unroll
    for (int ni = 0; ni < 4; ++ni) {
      int gcol = n0 + wn + ni * 16 + (lane & 15);
      float bv = bias[gcol];
      #pragma unroll
      for (int q = 0; q < 4; ++q) {
        int grow = m0 + wm + mi * 16 + ((lane >> 4) << 2) + q;
        float v = fmaxf(acc[mi][ni][q] + bv, 0.f);
        if (z < 4) E1[((size_t)z * B_ + grow) * 512 + gcol] = f2b(v);
        else       SH1E[(size_t)grow * 512 + gcol] = f2b(v);
      }
    }
}

// TOWER2 (mix1 fused, R10-proven): A-tile = t2[z] built during reg-staging.
__global__ __launch_bounds__(256) void k_tower2(const u16* __restrict__ E1,
    const u16* __restrict__ SH1E, const float* __restrict__ G1S,
    const u16* __restrict__ Wtw, const float* __restrict__ b_tw,
    const float* __restrict__ w_out, const float* __restrict__ b_out,
    float* __restrict__ out)
{
  __shared__ __align__(16) u16 sm[32768];
  __shared__ float part[2][128][2];
  f32x4 acc[4][4];
  const int z = blockIdx.z;
  const int m0 = blockIdx.x * 128;
  const int tid = threadIdx.x, lane = tid & 63, wave = tid >> 6;
  const int wm = ((tid >> 7) & 1) * 64, wn = ((tid >> 6) & 1) * 64;

  #pragma unroll
  for (int mi = 0; mi < 4; ++mi)
    #pragma unroll
    for (int ni = 0; ni < 4; ++ni) acc[mi][ni] = (f32x4){0.f, 0.f, 0.f, 0.f};

  const int srow  = lane >> 3;
  const int gslot = (lane & 7) ^ srow;
  const int koff0 = gslot * 8;

  int growA[4], adst[4], bdst[4];
  const u16* bsrc[4];
  #pragma unroll
  for (int i = 0; i < 4; ++i) {
    int c = wave * 4 + i;
    growA[i] = m0 + c * 8 + srow;
    adst[i]  = c * 512;
    bsrc[i]  = Wtw + (size_t)z * 128 * 256 + (size_t)(c * 8 + srow) * 256 + koff0;
    bdst[i]  = 8192 + c * 512;
  }
  const u16* E1z = E1 + (size_t)z * B_ * 512;

  int aoff[2][4], boff[2][4];
  #pragma unroll
  for (int kk = 0; kk < 2; ++kk) {
    #pragma unroll
    for (int m = 0; m < 4; ++m) {
      int r = wm + m * 16 + (lane & 15);
      aoff[kk][m] = r * 64 + (((kk * 4 + (lane >> 4)) ^ (r & 7)) * 8);
    }
    #pragma unroll
    for (int n = 0; n < 4; ++n) {
      int r = wn + n * 16 + (lane & 15);
      boff[kk][n] = 8192 + r * 64 + (((kk * 4 + (lane >> 4)) ^ (r & 7)) * 8);
    }
  }

  #define STAGE_T(J, BUF) do {                                                 \
    u16* buf_ = (BUF);                                                         \
    _Pragma("unroll")                                                          \
    for (int i_ = 0; i_ < 4; ++i_) {                                           \
      size_t eoff_ = (size_t)growA[i_] * 512 + (J) * 64 + koff0;               \
      u16x8 ea_ = *(const u16x8*)(E1z + eoff_);                                \
      u16x8 eb_ = *(const u16x8*)(E1z + eoff_ + 256);                          \
      u16x8 sa_ = *(const u16x8*)(SH1E + eoff_);                               \
      u16x8 sb_ = *(const u16x8*)(SH1E + eoff_ + 256);                         \
      float4 g_ = *(const float4*)(G1S + (size_t)growA[i_] * 16 + z * 4);      \
      u16x8 o_;                                                                \
      _Pragma("unroll")                                                        \
      for (int jj_ = 0; jj_ < 8; ++jj_)                                        \
        o_[jj_] = f2b(g_.x * b2f(ea_[jj_]) + g_.y * b2f(eb_[jj_])              \
                    + g_.z * b2f(sa_[jj_]) + g_.w * b2f(sb_[jj_]));            \
      *(uint4*)(buf_ + adst[i_] + lane * 8) = __builtin_bit_cast(uint4, o_);   \
      gload16(bsrc[i_] + (J) * 64, buf_ + bdst[i_]);                           \
    }                                                                          \
  } while (0)

  STAGE_T(0, sm);
  __syncthreads();

  #pragma unroll
  for (int t = 0; t < 4; ++t) {
    if (t + 1 < 4) STAGE_T(t + 1, sm + ((t + 1) & 1) * 16384);
    const u16* sa = sm + (t & 1) * 16384;
    #pragma unroll
    for (int kk = 0; kk < 2; ++kk) {
      bf16x8 av[4], bv[4];
      #pragma unroll
      for (int m = 0; m < 4; ++m) av[m] = *(const bf16x8*)(sa + aoff[kk][m]);
      #pragma unroll
      for (int n = 0; n < 4; ++n) bv[n] = *(const bf16x8*)(sa + boff[kk][n]);
      #pragma unroll
      for (int m = 0; m < 4; ++m)
        #pragma unroll
        for (int n = 0; n < 4; ++n)
          acc[m][n] = __builtin_amdgcn_mfma_f32_16x16x32_bf16(av[m], bv[n], acc[m][n], 0, 0, 0);
    }
    if (t + 1 < 4) __syncthreads();
  }
  #undef STAGE_T

  #pragma unroll
  for (int mi = 0; mi < 4; ++mi) {
    #pragma unroll
    for (int r = 0; r < 4; ++r) {
      float p0 = 0.f, p1 = 0.f;
      #pragma unroll
      for (int ni = 0; ni < 4; ++ni) {
        int col = wn + ni * 16 + (lane & 15);
        float h = fmaxf(acc[mi][ni][r] + b_tw[z * 128 + col], 0.f);
        p0 += h * w_out[(z * 128 + col) * 2 + 0];
        p1 += h * w_out[(z * 128 + col) * 2 + 1];
      }
      #pragma unroll
      for (int off = 1; off < 16; off <<= 1) {
        p0 += __shfl_xor(p0, off);
        p1 += __shfl_xor(p1, off);
      }
      if ((lane & 15) == 0) {
        int rowl = wm + mi * 16 + ((lane >> 4) << 2) + r;
        part[wn >> 6][rowl][0] = p0;
        part[wn >> 6][rowl][1] = p1;
      }
    }
  }
  __syncthreads();
  if (threadIdx.x < 128) {
    int rowl = threadIdx.x;
    float l0 = part[0][rowl][0] + part[1][rowl][0] + b_out[z * 2 + 0];
    float l1 = part[0][rowl][1] + part[1][rowl][1] + b_out[z * 2 + 1];
    float mx = fmaxf(l0, l1);
    float e0 = expf(l0 - mx), e1 = expf(l1 - mx);
    float inv = 1.f / (e0 + e1);
    float p0 = fminf(fmaxf(e0 * inv, 1e-15f), 1.0f);
    float p1 = fminf(fmaxf(e1 * inv, 1e-15f), 1.0f);
    size_t o = ((size_t)z * B_ + m0 + rowl) * 2;
    out[o] = p0; out[o + 1] = p1;
  }
}

// PREP: cast x -> bf16; transposed weight panels + biases + WG1T (gate1^T f32).
__global__ void k_prep(const float* __restrict__ x,
    const float* __restrict__ w_task0, const float* __restrict__ b_task0,
    const float* __restrict__ w_sh0,   const float* __restrict__ b_sh0,
    const float* __restrict__ w_gate0, const float* __restrict__ b_gate0,
    const float* __restrict__ w_gsh0,  const float* __restrict__ b_gsh0,
    const float* __restrict__ w_task1, const float* __restrict__ b_task1,
    const float* __restrict__ w_sh1,   const float* __restrict__ b_sh1,
    const float* __restrict__ w_gate1, const float* __restrict__ w_tw,
    u16* __restrict__ xb, u16* __restrict__ Wt0, float* __restrict__ bias0,
    u16* __restrict__ Wt1, float* __restrict__ bias1, u16* __restrict__ Wtw,
    float* __restrict__ WG1T)
{
  size_t i = (size_t)blockIdx.x * 256 + threadIdx.x;
  const size_t S_X8  = (size_t)16384 * 512 / 8; // 1048576
  const size_t S_WT0 = (size_t)2816 * 512;      // 1441792
  const size_t S_B0  = 2816;
  const size_t S_WT1 = (size_t)5 * 512 * 256;   // 655360
  const size_t S_B1  = 5 * 512;                 // 2560
  const size_t S_WTW = (size_t)4 * 128 * 256;   // 131072
  const size_t S_WG1 = 4096;

  if (i < S_X8) {
    size_t o = i * 8;
    float4 a = *(const float4*)(x + o);
    float4 b = *(const float4*)(x + o + 4);
    u16x8 v;
    v[0] = f2b(a.x); v[1] = f2b(a.y); v[2] = f2b(a.z); v[3] = f2b(a.w);
    v[4] = f2b(b.x); v[5] = f2b(b.y); v[6] = f2b(b.z); v[7] = f2b(b.w);
    *(u16x8*)(xb + o) = v;
    return;
  }
  i -= S_X8;
  if (i < S_WT0) {
    int c = (int)(i / 512), f = (int)(i % 512);
    float v = 0.f;
    if (c < 2048)      { int te = c >> 8, o = c & 255; v = w_task0[((size_t)te * 512 + f) * 256 + o]; }
    else if (c < 2560) { int s = (c - 2048) >> 8, o = c & 255; v = w_sh0[((size_t)s * 512 + f) * 256 + o]; }
    else if (c < 2576) { int q = c - 2560; int t = q >> 2, gg = q & 3; v = w_gate0[((size_t)t * 512 + f) * 4 + gg]; }
    else if (c < 2586) { int j = c - 2576; v = w_gsh0[(size_t)f * 10 + j]; }
    Wt0[i] = f2b(v);
    return;
  }
  i -= S_WT0;
  if (i < S_B0) {
    int c = (int)i; float v = 0.f;
    if (c < 2048)      { int te = c >> 8, o = c & 255; v = b_task0[te * 256 + o]; }
    else if (c < 2560) { int s = (c - 2048) >> 8, o = c & 255; v = b_sh0[s * 256 + o]; }
    else if (c < 2576) { v = b_gate0[c - 2560]; }
    else if (c < 2586) { v = b_gsh0[c - 2576]; }
    bias0[c] = v;
    return;
  }
  i -= S_B0;
  if (i < S_WT1) {
    int z = (int)(i / (512 * 256)); int rem = (int)(i % (512 * 256));
    int c = rem / 256, f = rem % 256;
    float v;
    if (z < 4) { int ee = c >> 8, o = c & 255; v = w_task1[(((size_t)(z * 2 + ee)) * 256 + f) * 256 + o]; }
    else       { int s = c >> 8, o = c & 255; v = w_sh1[((size_t)s * 256 + f) * 256 + o]; }
    Wt1[i] = f2b(v);
    return;
  }
  i -= S_WT1;
  if (i < S_B1) {
    int z = (int)(i / 512); int c = (int)(i % 512);
    float v;
    if (z < 4) { int ee = c >> 8, o = c & 255; v = b_task1[(z * 2 + ee) * 256 + o]; }
    else       { int s = c >> 8, o = c & 255; v = b_sh1[s * 256 + o]; }
    bias1[(size_t)z * 512 + c] = v;
    return;
  }
  i -= S_B1;
  if (i < S_WTW) {
    int z = (int)(i / (128 * 256)); int rem = (int)(i % (128 * 256));
    int h = rem / 256, f = rem % 256;
    Wtw[i] = f2b(w_tw[((size_t)z * 256 + f) * 128 + h]);
    return;
  }
  i -= S_WTW;
  if (i < S_WG1) {
    int t = (int)(i >> 10), gg = (int)((i >> 8) & 3), e = (int)(i & 255);
    WG1T[i] = w_gate1[((size_t)t * 256 + e) * 4 + gg];
    return;
  }
}

extern "C" void kernel_launch(void* const* d_in, const int* in_sizes, int n_in,
                              void* d_out, int out_size, void* d_ws, size_t ws_size,
                              hipStream_t stream)
{
  (void)in_sizes; (void)n_in; (void)out_size; (void)ws_size;
  const float* x       = (const float*)d_in[0];
  const float* w_task0 = (const float*)d_in[1];
  const float* b_task0 = (const float*)d_in[2];
  const float* w_sh0   = (const float*)d_in[3];
  const float* b_sh0   = (const float*)d_in[4];
  const float* w_gate0 = (const float*)d_in[5];
  const float* b_gate0 = (const float*)d_in[6];
  const float* w_gsh0  = (const float*)d_in[7];
  const float* b_gsh0  = (const float*)d_in[8];
  const float* w_task1 = (const float*)d_in[9];
  const float* b_task1 = (const float*)d_in[10];
  const float* w_sh1   = (const float*)d_in[11];
  const float* b_sh1   = (const float*)d_in[12];
  const float* w_gate1 = (const float*)d_in[13];
  const float* b_gate1 = (const float*)d_in[14];
  const float* w_tw    = (const float*)d_in[15];
  const float* b_tw    = (const float*)d_in[16];
  const float* w_out   = (const float*)d_in[17];
  const float* b_out   = (const float*)d_in[18];
  float* out = (float*)d_out;

  char* ws = (char*)d_ws;
  u16*   XB    = (u16*)  (ws + 0);            //  16,777,216  [16384][512] (dead after gemm0)
  u16*   SH1E  = (u16*)  (ws + 0);            //  reuses XB (first write: gemm1, after mix0 done)
  u16*   WT0   = (u16*)  (ws + 16777216);     //   2,883,584  [2816][512]
  float* BIAS0 = (float*)(ws + 19660800);     //      11,264  [2816]
  u16*   WT1   = (u16*)  (ws + 19672064);     //   1,310,720  [5][512][256]
  float* BIAS1 = (float*)(ws + 20982784);     //      10,240  [5][512]
  u16*   WTW   = (u16*)  (ws + 20993024);     //     262,144  [4][128][256]
  u16*   E0    = (u16*)  (ws + 21255168);     //  83,886,080  [16384][2560]
  float* G0L   = (float*)(ws + 105141248);    //   1,703,936  [16384][26]
  u16*   T1SH  = (u16*)  (ws + 106845184);    //  41,943,040  [5][16384][256]
  u16*   E1    = (u16*)  (ws + 148788224);    //  67,108,864  [4][16384][512]
  float* G1S   = (float*)(ws + 215897088);    //   1,048,576  [16384][16]
  float* WG1T  = (float*)(ws + 216945664);    //      16,384  [4][4][256]

  k_prep<<<12837, 256, 0, stream>>>(x, w_task0, b_task0, w_sh0, b_sh0, w_gate0, b_gate0,
      w_gsh0, b_gsh0, w_task1, b_task1, w_sh1, b_sh1, w_gate1, w_tw,
      XB, WT0, BIAS0, WT1, BIAS1, WTW, WG1T);
  k_gemm0<<<1408, 128, 0, stream>>>(XB, WT0, BIAS0, E0, G0L);
  k_mix0<<<2048, 256, 0, stream>>>(E0, G0L, WG1T, b_gate1, T1SH, G1S);
  k_gemm1<<<1280, 512, 0, stream>>>(T1SH, WT1, BIAS1, E1, SH1E);
  k_tower2<<<dim3(128, 1, 4), 256, 0, stream>>>(E1, SH1E, G1S, WTW, b_tw, w_out, b_out, out);
}

// Round 13
// 182.397 us; speedup vs baseline: 1.1635x; 1.1635x over previous
//
#include <hip/hip_runtime.h>

typedef unsigned short u16;
typedef __bf16 bf16x8 __attribute__((ext_vector_type(8)));
typedef float f32x4 __attribute__((ext_vector_type(4)));
typedef u16 u16x8 __attribute__((ext_vector_type(8)));

#define B_ 16384

__device__ __forceinline__ u16 f2b(float f){
  unsigned u = __builtin_bit_cast(unsigned, f);
  u = (u + 0x7FFFu + ((u >> 16) & 1u)) >> 16;   // RNE
  return (u16)u;
}
__device__ __forceinline__ float b2f(u16 v){
  return __builtin_bit_cast(float, ((unsigned)v) << 16);
}
__device__ __forceinline__ void ld8(const u16* __restrict__ p, float* f){
  u16x8 v = *(const u16x8*)p;
  #pragma unroll
  for (int j = 0; j < 8; ++j) f[j] = b2f(v[j]);
}
__device__ __forceinline__ void st8(u16* __restrict__ p, const float* f){
  u16x8 v;
  #pragma unroll
  for (int j = 0; j < 8; ++j) v[j] = f2b(f[j]);
  *(u16x8*)p = v;
}

__device__ __forceinline__ void gload16(const u16* g, u16* lds){
  __builtin_amdgcn_global_load_lds(
      (const __attribute__((address_space(1))) unsigned int*)g,
      (__attribute__((address_space(3))) unsigned int*)lds, 16, 0, 0);
}

// ===== core32 (R9/R10-proven): BM=256, BN=128, BK=32, ring-3, counted vmcnt =
// 0 bank conflicts (row-pair layout), 2 blocks/CU, 62.4us on gemm0.
__device__ __forceinline__ void core32(const u16* __restrict__ A,
                                       const u16* __restrict__ Wt,
                                       int K, int m0, int n0, int nt,
                                       u16* sm, f32x4 acc[4][4])
{
  const int tid = threadIdx.x, lane = tid & 63, wave = tid >> 6;
  const int wm = ((tid >> 7) & 3) * 64;
  const int wn = ((tid >> 6) & 1) * 64;

  #pragma unroll
  for (int m = 0; m < 4; ++m)
    #pragma unroll
    for (int n = 0; n < 4; ++n) acc[m][n] = (f32x4){0.f, 0.f, 0.f, 0.f};

  const int s_    = (lane & 7) ^ ((lane >> 3) & 7);
  const int srow2 = 2 * (lane >> 3) + (s_ >> 2);
  const int sk    = (s_ & 3) * 8;
  const u16* gsrc[3];
  int gdst[3];
  #pragma unroll
  for (int i = 0; i < 3; ++i) {
    int c = wave * 3 + i;
    if (c < 16) {
      gsrc[i] = A + (size_t)(m0 + c * 16 + srow2) * K + sk;
      gdst[i] = c * 512;
    } else {
      gsrc[i] = Wt + (size_t)(n0 + (c - 16) * 16 + srow2) * K + sk;
      gdst[i] = 8192 + (c - 16) * 512;
    }
  }

  int aoff[4], boff[4];
  #pragma unroll
  for (int m = 0; m < 4; ++m) {
    int r = wm + m * 16 + (lane & 15);
    int L = r >> 1;
    int phys = (((r & 1) << 2) + (lane >> 4)) ^ (L & 7);
    aoff[m] = L * 64 + phys * 8;
  }
  #pragma unroll
  for (int n = 0; n < 4; ++n) {
    int r = wn + n * 16 + (lane & 15);
    int L = r >> 1;
    int phys = (((r & 1) << 2) + (lane >> 4)) ^ (L & 7);
    boff[n] = 8192 + L * 64 + phys * 8;
  }

  #pragma unroll
  for (int j = 0; j < 2; ++j) {
    u16* sl = sm + j * 12288;
    #pragma unroll
    for (int i = 0; i < 3; ++i) gload16(gsrc[i] + j * 32, sl + gdst[i]);
  }
  asm volatile("s_waitcnt vmcnt(3)" ::: "memory");
  __builtin_amdgcn_s_barrier();

  int cs = 0;
  for (int j = 0; j < nt; ++j) {
    if (j + 2 < nt) {
      int ns = cs + 2; ns = (ns >= 3) ? ns - 3 : ns;
      u16* sl = sm + ns * 12288;
      #pragma unroll
      for (int i = 0; i < 3; ++i) gload16(gsrc[i] + (size_t)(j + 2) * 32, sl + gdst[i]);
    }
    const u16* sa = sm + cs * 12288;
    bf16x8 av[4], bv[4];
    #pragma unroll
    for (int m = 0; m < 4; ++m) av[m] = *(const bf16x8*)(sa + aoff[m]);
    #pragma unroll
    for (int n = 0; n < 4; ++n) bv[n] = *(const bf16x8*)(sa + boff[n]);
    __builtin_amdgcn_s_setprio(1);
    #pragma unroll
    for (int m = 0; m < 4; ++m)
      #pragma unroll
      for (int n = 0; n < 4; ++n)
        acc[m][n] = __builtin_amdgcn_mfma_f32_16x16x32_bf16(av[m], bv[n], acc[m][n], 0, 0, 0);
    __builtin_amdgcn_s_setprio(0);
    if (j + 2 < nt)      asm volatile("s_waitcnt vmcnt(3)" ::: "memory");
    else if (j + 1 < nt) asm volatile("s_waitcnt vmcnt(0)" ::: "memory");
    __builtin_amdgcn_s_barrier();
    cs = (cs == 2) ? 0 : cs + 1;
  }
}

// ---------------- stage kernels ----------------

// GEMM0 (R10-proven): xb[16384,512] x Wt0[2816,512]^T. grid 1344, XCD-swizzled.
__global__ __launch_bounds__(512) void k_gemm0(const u16* __restrict__ xb,
    const u16* __restrict__ Wt0, const float* __restrict__ bias0,
    u16* __restrict__ E0, float* __restrict__ G0L)
{
  __shared__ __align__(16) u16 sm[36864];
  f32x4 acc[4][4];
  const int bid = blockIdx.x;                 // 1344 = 8 * 168
  const int swz = (bid & 7) * 168 + (bid >> 3);
  const int m0 = (swz / 21) * 256, n0 = (swz % 21) * 128;
  core32(xb, Wt0, 512, m0, n0, 16, sm, acc);
  const int lane = threadIdx.x & 63;
  const int wm = ((threadIdx.x >> 7) & 3) * 64, wn = ((threadIdx.x >> 6) & 1) * 64;
  #pragma unroll
  for (int mi = 0; mi < 4; ++mi)
    #pragma unroll
    for (int ni = 0; ni < 4; ++ni) {
      int gcol = n0 + wn + ni * 16 + (lane & 15);
      float bias = bias0[gcol];
      #pragma unroll
      for (int q = 0; q < 4; ++q) {
        int grow = m0 + wm + mi * 16 + ((lane >> 4) << 2) + q;
        float v = acc[mi][ni][q] + bias;
        if (gcol < 2560)      E0[(size_t)grow * 2560 + gcol] = f2b(fmaxf(v, 0.f));
        else if (gcol < 2586) G0L[(size_t)grow * 26 + (gcol - 2560)] = v;
      }
    }
}

// MIX0 + fused gate1 (R10-proven): 8 rows/block, 32-lane half-wave per row.
__global__ __launch_bounds__(256) void k_mix0(const u16* __restrict__ E0,
    const float* __restrict__ G0L, const float* __restrict__ WG1T,
    const float* __restrict__ b_gate1, u16* __restrict__ T1SH,
    float* __restrict__ G1S)
{
  const int b = blockIdx.x * 8 + (threadIdx.x >> 5);
  const int e0 = (threadIdx.x & 31) * 8;
  const float* gl = G0L + (size_t)b * 26;
  float g[4][4];
  #pragma unroll
  for (int t = 0; t < 4; ++t) {
    float l0 = gl[t*4+0], l1 = gl[t*4+1], l2 = gl[t*4+2], l3 = gl[t*4+3];
    float m = fmaxf(fmaxf(l0, l1), fmaxf(l2, l3));
    float e0e = expf(l0-m), e1 = expf(l1-m), e2 = expf(l2-m), e3 = expf(l3-m);
    float inv = 1.f / (e0e + e1 + e2 + e3);
    g[t][0] = e0e*inv; g[t][1] = e1*inv; g[t][2] = e2*inv; g[t][3] = e3*inv;
  }
  float gs[10];
  {
    float m = gl[16];
    #pragma unroll
    for (int j = 1; j < 10; ++j) m = fmaxf(m, gl[16 + j]);
    float s = 0.f;
    #pragma unroll
    for (int j = 0; j < 10; ++j) { gs[j] = expf(gl[16 + j] - m); s += gs[j]; }
    float inv = 1.f / s;
    #pragma unroll
    for (int j = 0; j < 10; ++j) gs[j] *= inv;
  }
  const u16* row = E0 + (size_t)b * 2560;
  float sh0[8], sh1[8], shacc[8];
  ld8(row + 2048 + e0, sh0);
  ld8(row + 2304 + e0, sh1);
  #pragma unroll
  for (int j = 0; j < 8; ++j) shacc[j] = gs[8]*sh0[j] + gs[9]*sh1[j];
  float gp[16];
  #pragma unroll
  for (int t = 0; t < 4; ++t) {
    float te0[8], te1[8], v[8];
    ld8(row + (t*2+0)*256 + e0, te0);
    ld8(row + (t*2+1)*256 + e0, te1);
    #pragma unroll
    for (int j = 0; j < 8; ++j) {
      v[j] = g[t][0]*te0[j] + g[t][1]*te1[j] + g[t][2]*sh0[j] + g[t][3]*sh1[j];
      shacc[j] += gs[t*2+0]*te0[j] + gs[t*2+1]*te1[j];
    }
    st8(T1SH + ((size_t)t * B_ + b) * 256 + e0, v);
    #pragma unroll
    for (int gg = 0; gg < 4; ++gg) {
      const float* wv = WG1T + ((size_t)(t * 4 + gg) * 256 + e0);
      float s = 0.f;
      #pragma unroll
      for (int j = 0; j < 8; ++j) s += v[j] * wv[j];
      gp[t * 4 + gg] = s;
    }
  }
  st8(T1SH + ((size_t)4 * B_ + b) * 256 + e0, shacc);
  #pragma unroll
  for (int i = 0; i < 16; ++i) {
    #pragma unroll
    for (int off = 1; off < 32; off <<= 1)
      gp[i] += __shfl_xor(gp[i], off, 32);
  }
  if ((threadIdx.x & 31) == 0) {
    float* orow = G1S + (size_t)b * 16;
    #pragma unroll
    for (int z = 0; z < 4; ++z) {
      float l0 = gp[z*4+0] + b_gate1[z*4+0];
      float l1 = gp[z*4+1] + b_gate1[z*4+1];
      float l2 = gp[z*4+2] + b_gate1[z*4+2];
      float l3 = gp[z*4+3] + b_gate1[z*4+3];
      float m = fmaxf(fmaxf(l0, l1), fmaxf(l2, l3));
      float x0 = expf(l0-m), x1 = expf(l1-m), x2 = expf(l2-m), x3 = expf(l3-m);
      float inv = 1.f / (x0 + x1 + x2 + x3);
      orow[z*4+0] = x0*inv; orow[z*4+1] = x1*inv;
      orow[z*4+2] = x2*inv; orow[z*4+3] = x3*inv;
    }
  }
}

// GEMM1 v2: continuous-ring 2-tile. 640 blocks; block handles tiles (mi_, pan)
// and (mi_+32, pan): same z/n0 (B pointers + L2 panel shared), m0 +8192 rows.
// Ring runs 16 uninterrupted steps (slot = s%3); tile-2 stages issue while
// tile-1's last MFMAs run; C-write of tile 1 sits between barriers (stores
// inflate vmcnt once -> one over-wait at end of s=8, correct by in-order
// retirement). Waits: vmcnt(3) steady, vmcnt(0) only at s=14.
__global__ __launch_bounds__(512) void k_gemm1(const u16* __restrict__ T1SH,
    const u16* __restrict__ Wt1, const float* __restrict__ bias1,
    u16* __restrict__ E1, u16* __restrict__ SH1E)
{
  __shared__ __align__(16) u16 sm[36864];
  f32x4 acc[4][4];
  const int bid = blockIdx.x;                 // 640 = 8 * 80
  const int swz = (bid & 7) * 80 + (bid >> 3);
  const int mi_ = swz / 20, pan = swz % 20;
  const int z  = pan >> 2;
  const int n0 = (pan & 3) * 128;
  const int m0 = mi_ * 256;                   // tile 0; tile 1 = m0 + 8192
  const u16* A  = T1SH + (size_t)z * B_ * 256;
  const u16* Wt = Wt1 + (size_t)z * 512 * 256;
  const int K = 256;
  const size_t AOFF = (size_t)8192 * 256;

  const int tid = threadIdx.x, lane = tid & 63, wave = tid >> 6;
  const int wm = ((tid >> 7) & 3) * 64;
  const int wn = ((tid >> 6) & 1) * 64;

  #pragma unroll
  for (int m = 0; m < 4; ++m)
    #pragma unroll
    for (int n = 0; n < 4; ++n) acc[m][n] = (f32x4){0.f, 0.f, 0.f, 0.f};

  const int s_    = (lane & 7) ^ ((lane >> 3) & 7);
  const int srow2 = 2 * (lane >> 3) + (s_ >> 2);
  const int sk    = (s_ & 3) * 8;
  const u16* gsrc[3];
  int gdst[3];
  bool aA[3];
  #pragma unroll
  for (int i = 0; i < 3; ++i) {
    int c = wave * 3 + i;
    if (c < 16) {
      aA[i] = true;
      gsrc[i] = A + (size_t)(m0 + c * 16 + srow2) * K + sk;
      gdst[i] = c * 512;
    } else {
      aA[i] = false;
      gsrc[i] = Wt + (size_t)(n0 + (c - 16) * 16 + srow2) * K + sk;
      gdst[i] = 8192 + (c - 16) * 512;
    }
  }

  int aoff[4], boff[4];
  #pragma unroll
  for (int m = 0; m < 4; ++m) {
    int r = wm + m * 16 + (lane & 15);
    int L = r >> 1;
    int phys = (((r & 1) << 2) + (lane >> 4)) ^ (L & 7);
    aoff[m] = L * 64 + phys * 8;
  }
  #pragma unroll
  for (int n = 0; n < 4; ++n) {
    int r = wn + n * 16 + (lane & 15);
    int L = r >> 1;
    int phys = (((r & 1) << 2) + (lane >> 4)) ^ (L & 7);
    boff[n] = 8192 + L * 64 + phys * 8;
  }

  // prologue: stage global steps 0,1 (tile 0, j=0,1) into slots 0,1
  #pragma unroll
  for (int j = 0; j < 2; ++j) {
    u16* sl = sm + j * 12288;
    #pragma unroll
    for (int i = 0; i < 3; ++i) gload16(gsrc[i] + j * 32, sl + gdst[i]);
  }
  asm volatile("s_waitcnt vmcnt(3)" ::: "memory");
  __builtin_amdgcn_s_barrier();

  const float* bias = bias1 + z * 512;
  for (int tt = 0; tt < 2; ++tt) {
    for (int j = 0; j < 8; ++j) {
      const int s = tt * 8 + j;
      const int ss = s + 2;
      if (ss < 16) {
        const int jt = ss >> 3, jj = ss & 7;
        u16* sl = sm + (ss % 3) * 12288;
        #pragma unroll
        for (int i = 0; i < 3; ++i) {
          const u16* src = gsrc[i] + (size_t)jj * 32 + ((aA[i] && jt) ? AOFF : 0);
          gload16(src, sl + gdst[i]);
        }
      }
      const u16* sa = sm + (s % 3) * 12288;
      bf16x8 av[4], bv[4];
      #pragma unroll
      for (int m = 0; m < 4; ++m) av[m] = *(const bf16x8*)(sa + aoff[m]);
      #pragma unroll
      for (int n = 0; n < 4; ++n) bv[n] = *(const bf16x8*)(sa + boff[n]);
      __builtin_amdgcn_s_setprio(1);
      #pragma unroll
      for (int m = 0; m < 4; ++m)
        #pragma unroll
        for (int n = 0; n < 4; ++n)
          acc[m][n] = __builtin_amdgcn_mfma_f32_16x16x32_bf16(av[m], bv[n], acc[m][n], 0, 0, 0);
      __builtin_amdgcn_s_setprio(0);
      if (ss < 16)          asm volatile("s_waitcnt vmcnt(3)" ::: "memory");
      else if (s + 1 < 16)  asm volatile("s_waitcnt vmcnt(0)" ::: "memory");
      __builtin_amdgcn_s_barrier();
    }
    // epilogue for tile tt (C-stores overlap the already-issued next stages)
    const int mbase = m0 + tt * 8192;
    #pragma unroll
    for (int mi = 0; mi < 4; ++mi)
      #pragma unroll
      for (int ni = 0; ni < 4; ++ni) {
        int gcol = n0 + wn + ni * 16 + (lane & 15);
        float bv2 = bias[gcol];
        #pragma unroll
        for (int q = 0; q < 4; ++q) {
          int grow = mbase + wm + mi * 16 + ((lane >> 4) << 2) + q;
          float v = fmaxf(acc[mi][ni][q] + bv2, 0.f);
          if (z < 4) E1[((size_t)z * B_ + grow) * 512 + gcol] = f2b(v);
          else       SH1E[(size_t)grow * 512 + gcol] = f2b(v);
        }
      }
    if (tt == 0) {
      #pragma unroll
      for (int m = 0; m < 4; ++m)
        #pragma unroll
        for (int n = 0; n < 4; ++n) acc[m][n] = (f32x4){0.f, 0.f, 0.f, 0.f};
    }
  }
}

// TOWER2 (mix1 fused, R10-proven): A-tile = t2[z] built during reg-staging.
__global__ __launch_bounds__(256) void k_tower2(const u16* __restrict__ E1,
    const u16* __restrict__ SH1E, const float* __restrict__ G1S,
    const u16* __restrict__ Wtw, const float* __restrict__ b_tw,
    const float* __restrict__ w_out, const float* __restrict__ b_out,
    float* __restrict__ out)
{
  __shared__ __align__(16) u16 sm[32768];
  __shared__ float part[2][128][2];
  f32x4 acc[4][4];
  const int z = blockIdx.z;
  const int m0 = blockIdx.x * 128;
  const int tid = threadIdx.x, lane = tid & 63, wave = tid >> 6;
  const int wm = ((tid >> 7) & 1) * 64, wn = ((tid >> 6) & 1) * 64;

  #pragma unroll
  for (int mi = 0; mi < 4; ++mi)
    #pragma unroll
    for (int ni = 0; ni < 4; ++ni) acc[mi][ni] = (f32x4){0.f, 0.f, 0.f, 0.f};

  const int srow  = lane >> 3;
  const int gslot = (lane & 7) ^ srow;
  const int koff0 = gslot * 8;

  int growA[4], adst[4], bdst[4];
  const u16* bsrc[4];
  #pragma unroll
  for (int i = 0; i < 4; ++i) {
    int c = wave * 4 + i;
    growA[i] = m0 + c * 8 + srow;
    adst[i]  = c * 512;
    bsrc[i]  = Wtw + (size_t)z * 128 * 256 + (size_t)(c * 8 + srow) * 256 + koff0;
    bdst[i]  = 8192 + c * 512;
  }
  const u16* E1z = E1 + (size_t)z * B_ * 512;

  int aoff[2][4], boff[2][4];
  #pragma unroll
  for (int kk = 0; kk < 2; ++kk) {
    #pragma unroll
    for (int m = 0; m < 4; ++m) {
      int r = wm + m * 16 + (lane & 15);
      aoff[kk][m] = r * 64 + (((kk * 4 + (lane >> 4)) ^ (r & 7)) * 8);
    }
    #pragma unroll
    for (int n = 0; n < 4; ++n) {
      int r = wn + n * 16 + (lane & 15);
      boff[kk][n] = 8192 + r * 64 + (((kk * 4 + (lane >> 4)) ^ (r & 7)) * 8);
    }
  }

  #define STAGE_T(J, BUF) do {                                                 \
    u16* buf_ = (BUF);                                                         \
    _Pragma("unroll")                                                          \
    for (int i_ = 0; i_ < 4; ++i_) {                                           \
      size_t eoff_ = (size_t)growA[i_] * 512 + (J) * 64 + koff0;               \
      u16x8 ea_ = *(const u16x8*)(E1z + eoff_);                                \
      u16x8 eb_ = *(const u16x8*)(E1z + eoff_ + 256);                          \
      u16x8 sa_ = *(const u16x8*)(SH1E + eoff_);                               \
      u16x8 sb_ = *(const u16x8*)(SH1E + eoff_ + 256);                         \
      float4 g_ = *(const float4*)(G1S + (size_t)growA[i_] * 16 + z * 4);      \
      u16x8 o_;                                                                \
      _Pragma("unroll")                                                        \
      for (int jj_ = 0; jj_ < 8; ++jj_)                                        \
        o_[jj_] = f2b(g_.x * b2f(ea_[jj_]) + g_.y * b2f(eb_[jj_])              \
                    + g_.z * b2f(sa_[jj_]) + g_.w * b2f(sb_[jj_]));            \
      *(uint4*)(buf_ + adst[i_] + lane * 8) = __builtin_bit_cast(uint4, o_);   \
      gload16(bsrc[i_] + (J) * 64, buf_ + bdst[i_]);                           \
    }                                                                          \
  } while (0)

  STAGE_T(0, sm);
  __syncthreads();

  #pragma unroll
  for (int t = 0; t < 4; ++t) {
    if (t + 1 < 4) STAGE_T(t + 1, sm + ((t + 1) & 1) * 16384);
    const u16* sa = sm + (t & 1) * 16384;
    #pragma unroll
    for (int kk = 0; kk < 2; ++kk) {
      bf16x8 av[4], bv[4];
      #pragma unroll
      for (int m = 0; m < 4; ++m) av[m] = *(const bf16x8*)(sa + aoff[kk][m]);
      #pragma unroll
      for (int n = 0; n < 4; ++n) bv[n] = *(const bf16x8*)(sa + boff[kk][n]);
      #pragma unroll
      for (int m = 0; m < 4; ++m)
        #pragma unroll
        for (int n = 0; n < 4; ++n)
          acc[m][n] = __builtin_amdgcn_mfma_f32_16x16x32_bf16(av[m], bv[n], acc[m][n], 0, 0, 0);
    }
    if (t + 1 < 4) __syncthreads();
  }
  #undef STAGE_T

  #pragma unroll
  for (int mi = 0; mi < 4; ++mi) {
    #pragma unroll
    for (int r = 0; r < 4; ++r) {
      float p0 = 0.f, p1 = 0.f;
      #pragma unroll
      for (int ni = 0; ni < 4; ++ni) {
        int col = wn + ni * 16 + (lane & 15);
        float h = fmaxf(acc[mi][ni][r] + b_tw[z * 128 + col], 0.f);
        p0 += h * w_out[(z * 128 + col) * 2 + 0];
        p1 += h * w_out[(z * 128 + col) * 2 + 1];
      }
      #pragma unroll
      for (int off = 1; off < 16; off <<= 1) {
        p0 += __shfl_xor(p0, off);
        p1 += __shfl_xor(p1, off);
      }
      if ((lane & 15) == 0) {
        int rowl = wm + mi * 16 + ((lane >> 4) << 2) + r;
        part[wn >> 6][rowl][0] = p0;
        part[wn >> 6][rowl][1] = p1;
      }
    }
  }
  __syncthreads();
  if (threadIdx.x < 128) {
    int rowl = threadIdx.x;
    float l0 = part[0][rowl][0] + part[1][rowl][0] + b_out[z * 2 + 0];
    float l1 = part[0][rowl][1] + part[1][rowl][1] + b_out[z * 2 + 1];
    float mx = fmaxf(l0, l1);
    float e0 = expf(l0 - mx), e1 = expf(l1 - mx);
    float inv = 1.f / (e0 + e1);
    float p0 = fminf(fmaxf(e0 * inv, 1e-15f), 1.0f);
    float p1 = fminf(fmaxf(e1 * inv, 1e-15f), 1.0f);
    size_t o = ((size_t)z * B_ + m0 + rowl) * 2;
    out[o] = p0; out[o + 1] = p1;
  }
}

// PREP (R10-proven): cast x -> bf16; weight panels + biases + WG1T.
__global__ void k_prep(const float* __restrict__ x,
    const float* __restrict__ w_task0, const float* __restrict__ b_task0,
    const float* __restrict__ w_sh0,   const float* __restrict__ b_sh0,
    const float* __restrict__ w_gate0, const float* __restrict__ b_gate0,
    const float* __restrict__ w_gsh0,  const float* __restrict__ b_gsh0,
    const float* __restrict__ w_task1, const float* __restrict__ b_task1,
    const float* __restrict__ w_sh1,   const float* __restrict__ b_sh1,
    const float* __restrict__ w_gate1, const float* __restrict__ w_tw,
    u16* __restrict__ xb, u16* __restrict__ Wt0, float* __restrict__ bias0,
    u16* __restrict__ Wt1, float* __restrict__ bias1, u16* __restrict__ Wtw,
    float* __restrict__ WG1T)
{
  size_t i = (size_t)blockIdx.x * 256 + threadIdx.x;
  const size_t S_X8  = (size_t)16384 * 512 / 8; // 1048576
  const size_t S_WT0 = (size_t)2816 * 512;      // 1441792
  const size_t S_B0  = 2816;
  const size_t S_WT1 = (size_t)5 * 512 * 256;   // 655360
  const size_t S_B1  = 5 * 512;                 // 2560
  const size_t S_WTW = (size_t)4 * 128 * 256;   // 131072
  const size_t S_WG1 = 4096;

  if (i < S_X8) {
    size_t o = i * 8;
    float4 a = *(const float4*)(x + o);
    float4 b = *(const float4*)(x + o + 4);
    u16x8 v;
    v[0] = f2b(a.x); v[1] = f2b(a.y); v[2] = f2b(a.z); v[3] = f2b(a.w);
    v[4] = f2b(b.x); v[5] = f2b(b.y); v[6] = f2b(b.z); v[7] = f2b(b.w);
    *(u16x8*)(xb + o) = v;
    return;
  }
  i -= S_X8;
  if (i < S_WT0) {
    int c = (int)(i / 512), f = (int)(i % 512);
    float v = 0.f;
    if (c < 2048)      { int te = c >> 8, o = c & 255; v = w_task0[((size_t)te * 512 + f) * 256 + o]; }
    else if (c < 2560) { int s = (c - 2048) >> 8, o = c & 255; v = w_sh0[((size_t)s * 512 + f) * 256 + o]; }
    else if (c < 2576) { int q = c - 2560; int t = q >> 2, gg = q & 3; v = w_gate0[((size_t)t * 512 + f) * 4 + gg]; }
    else if (c < 2586) { int j = c - 2576; v = w_gsh0[(size_t)f * 10 + j]; }
    Wt0[i] = f2b(v);
    return;
  }
  i -= S_WT0;
  if (i < S_B0) {
    int c = (int)i; float v = 0.f;
    if (c < 2048)      { int te = c >> 8, o = c & 255; v = b_task0[te * 256 + o]; }
    else if (c < 2560) { int s = (c - 2048) >> 8, o = c & 255; v = b_sh0[s * 256 + o]; }
    else if (c < 2576) { v = b_gate0[c - 2560]; }
    else if (c < 2586) { v = b_gsh0[c - 2576]; }
    bias0[c] = v;
    return;
  }
  i -= S_B0;
  if (i < S_WT1) {
    int z = (int)(i / (512 * 256)); int rem = (int)(i % (512 * 256));
    int c = rem / 256, f = rem % 256;
    float v;
    if (z < 4) { int ee = c >> 8, o = c & 255; v = w_task1[(((size_t)(z * 2 + ee)) * 256 + f) * 256 + o]; }
    else       { int s = c >> 8, o = c & 255; v = w_sh1[((size_t)s * 256 + f) * 256 + o]; }
    Wt1[i] = f2b(v);
    return;
  }
  i -= S_WT1;
  if (i < S_B1) {
    int z = (int)(i / 512); int c = (int)(i % 512);
    float v;
    if (z < 4) { int ee = c >> 8, o = c & 255; v = b_task1[(z * 2 + ee) * 256 + o]; }
    else       { int s = c >> 8, o = c & 255; v = b_sh1[s * 256 + o]; }
    bias1[(size_t)z * 512 + c] = v;
    return;
  }
  i -= S_B1;
  if (i < S_WTW) {
    int z = (int)(i / (128 * 256)); int rem = (int)(i % (128 * 256));
    int h = rem / 256, f = rem % 256;
    Wtw[i] = f2b(w_tw[((size_t)z * 256 + f) * 128 + h]);
    return;
  }
  i -= S_WTW;
  if (i < S_WG1) {
    int t = (int)(i >> 10), gg = (int)((i >> 8) & 3), e = (int)(i & 255);
    WG1T[i] = w_gate1[((size_t)t * 256 + e) * 4 + gg];
    return;
  }
}

extern "C" void kernel_launch(void* const* d_in, const int* in_sizes, int n_in,
                              void* d_out, int out_size, void* d_ws, size_t ws_size,
                              hipStream_t stream)
{
  (void)in_sizes; (void)n_in; (void)out_size; (void)ws_size;
  const float* x       = (const float*)d_in[0];
  const float* w_task0 = (const float*)d_in[1];
  const float* b_task0 = (const float*)d_in[2];
  const float* w_sh0   = (const float*)d_in[3];
  const float* b_sh0   = (const float*)d_in[4];
  const float* w_gate0 = (const float*)d_in[5];
  const float* b_gate0 = (const float*)d_in[6];
  const float* w_gsh0  = (const float*)d_in[7];
  const float* b_gsh0  = (const float*)d_in[8];
  const float* w_task1 = (const float*)d_in[9];
  const float* b_task1 = (const float*)d_in[10];
  const float* w_sh1   = (const float*)d_in[11];
  const float* b_sh1   = (const float*)d_in[12];
  const float* w_gate1 = (const float*)d_in[13];
  const float* b_gate1 = (const float*)d_in[14];
  const float* w_tw    = (const float*)d_in[15];
  const float* b_tw    = (const float*)d_in[16];
  const float* w_out   = (const float*)d_in[17];
  const float* b_out   = (const float*)d_in[18];
  float* out = (float*)d_out;

  char* ws = (char*)d_ws;
  u16*   XB    = (u16*)  (ws + 0);            //  16,777,216  [16384][512] (dead after gemm0/mix0)
  u16*   SH1E  = (u16*)  (ws + 0);            //  reuses XB (first write: gemm1)
  u16*   WT0   = (u16*)  (ws + 16777216);     //   2,883,584  [2816][512]
  float* BIAS0 = (float*)(ws + 19660800);     //      11,264  [2816]
  u16*   WT1   = (u16*)  (ws + 19672064);     //   1,310,720  [5][512][256]
  float* BIAS1 = (float*)(ws + 20982784);     //      10,240  [5][512]
  u16*   WTW   = (u16*)  (ws + 20993024);     //     262,144  [4][128][256]
  u16*   E0    = (u16*)  (ws + 21255168);     //  83,886,080  [16384][2560]
  float* G0L   = (float*)(ws + 105141248);    //   1,703,936  [16384][26]
  u16*   T1SH  = (u16*)  (ws + 106845184);    //  41,943,040  [5][16384][256]
  u16*   E1    = (u16*)  (ws + 148788224);    //  67,108,864  [4][16384][512]
  float* G1S   = (float*)(ws + 215897088);    //   1,048,576  [16384][16]
  float* WG1T  = (float*)(ws + 216945664);    //      16,384  [4][4][256]

  k_prep<<<12837, 256, 0, stream>>>(x, w_task0, b_task0, w_sh0, b_sh0, w_gate0, b_gate0,
      w_gsh0, b_gsh0, w_task1, b_task1, w_sh1, b_sh1, w_gate1, w_tw,
      XB, WT0, BIAS0, WT1, BIAS1, WTW, WG1T);
  k_gemm0<<<1344, 512, 0, stream>>>(XB, WT0, BIAS0, E0, G0L);
  k_mix0<<<2048, 256, 0, stream>>>(E0, G0L, WG1T, b_gate1, T1SH, G1S);
  k_gemm1<<<640, 512, 0, stream>>>(T1SH, WT1, BIAS1, E1, SH1E);
  k_tower2<<<dim3(128, 1, 4), 256, 0, stream>>>(E1, SH1E, G1S, WTW, b_tw, w_out, b_out, out);
}